// Round 3
// baseline (775.442 us; speedup 1.0000x reference)
//
#include <hip/hip_runtime.h>
#include <stdint.h>

// ---------------------------------------------------------------------------
// RPN FPN head, MI355X (gfx950).
// conv3x3(256->512)+ReLU as implicit GEMM, 256^2 tile / 512 thr / 8 waves,
// BK=64, double-buffered 128 KiB LDS, 2 raw s_barrier per K-tile and NO
// forced lgkm drains: plain ds_reads let the compiler emit counted
// lgkmcnt(N) so reads interleave under MFMAs (m97 evidence). Barrier (i)
// (after Q2) gates STAGE_B(t+2) vs all waves' B-reads -- implied drained by
// MFMA operand waits. Barrier (ii) gates the buffer flip after counted
// vmcnt(4) (B staged 2 tiles ahead, A 1 tile ahead stay in flight).
// setprio(1) around MFMA clusters, XOR-swizzled LDS slots, bijective XCD
// grid swizzle. Fused 1x1 heads via small MFMA + atomicAdd partials;
// finalize does biases + paired softmax.
//
// Workspace layout (bytes):
//   [0,        2359296)   Wr2  bf16 [512 o][2304 k]   (B^T conv weights, k=(kh,kw,c))
//   [2359296,  2392064)   Wh2  bf16 [32 j][512 o]     (cls 0..5, box 6..17, 18..31 zero)
//   [2392064, 17100800)   sbuf f32  [204288 slot][18] (head partial sums; memset 0)
//   [17100800,123197440)  fpad bf16 padded NHWC feats (only pad RINGS zeroed;
//                         guard/overrun cells may hold poison -> outputs discarded)
// ---------------------------------------------------------------------------

typedef __bf16 bf16x8 __attribute__((ext_vector_type(8)));
typedef float  f32x4  __attribute__((ext_vector_type(4)));

#define WS_WR2_OFF   0
#define WS_WH2_OFF   2359296
#define WS_SB_OFF    2392064
#define WS_FP_OFF    17100800
#define WS_TOTAL     123197440

__device__ __forceinline__ unsigned short f2bf(float f) {
    unsigned u = __builtin_bit_cast(unsigned, f);
    unsigned r = (u + 0x7FFF + ((u >> 16) & 1)) >> 16;
    return (unsigned short)r;
}

__device__ __forceinline__ void gl_lds16(const void* g, void* l) {
    __builtin_amdgcn_global_load_lds(
        (const __attribute__((address_space(1))) unsigned int*)g,
        (__attribute__((address_space(3))) unsigned int*)l, 16, 0, 0);
}

// ---------------------------------------------------------------------------
// Kernel 1: weight repack.  Wr2[o*2304 + (r*256+c)] = bf16(W_conv[o][c][kh][kw]),
// r = kh*3+kw.  Wh2[j*512+o] = cls (j<6) / box (6<=j<18) / 0 (18<=j<32).
// ---------------------------------------------------------------------------
__global__ __launch_bounds__(256) void prep_weights(
    const float* __restrict__ Wc, const float* __restrict__ Wcls,
    const float* __restrict__ Wbox,
    unsigned short* __restrict__ wr2, unsigned short* __restrict__ wh2)
{
    int idx = blockIdx.x * 256 + threadIdx.x;
    if (idx < 1179648) {
        int o = idx / 2304;
        int k = idx - o * 2304;
        int r = k >> 8, c = k & 255;
        wr2[idx] = f2bf(Wc[o * 2304 + c * 9 + r]);
    } else {
        int i2 = idx - 1179648;
        if (i2 < 16384) {
            int j = i2 >> 9, o = i2 & 511;
            float v = (j < 6) ? Wcls[j * 512 + o]
                    : (j < 18) ? Wbox[(j - 6) * 512 + o] : 0.0f;
            wh2[j * 512 + o] = f2bf(v);
        }
    }
}

// ---------------------------------------------------------------------------
// Kernel 1b: zero the SAME-padding rings of each (b, level) padded image.
// ---------------------------------------------------------------------------
__global__ __launch_bounds__(256) void zero_rings(unsigned short* __restrict__ fpad)
{
    int idx = blockIdx.x * 256 + threadIdx.x;        // < 201728 = 4 * 50432
    int b = idx / 50432;
    int rem = idx - b * 50432;
    int Wp, H, W; long lb;
    if (rem < 25728)      {               Wp=252; H=150; W=250; lb=32768    + (long)b*9805824; }
    else if (rem < 38656) { rem -= 25728; Wp=127; H=75;  W=125; lb=39288832 + (long)b*2503424; }
    else if (rem < 45248) { rem -= 38656; Wp=65;  H=38;  W=63;  lb=49335296 + (long)b*665600;  }
    else if (rem < 48640) { rem -= 45248; Wp=34;  H=19;  W=32;  lb=52030464 + (long)b*182784;  }
    else                  { rem -= 48640; Wp=18;  H=10;  W=16;  lb=52794368 + (long)b*55296;   }
    int c = rem >> 5, slot = rem & 31;
    int h, w;
    if (c < Wp)          { h = 0;     w = c; }
    else if (c < 2 * Wp) { h = H + 1; w = c - Wp; }
    else {
        int c2 = c - 2 * Wp;
        h = 1 + (c2 >> 1);
        w = (c2 & 1) ? (W + 1) : 0;
    }
    uint4 z = {0u, 0u, 0u, 0u};
    *(uint4*)(fpad + lb + (long)(h * Wp + w) * 256 + slot * 8) = z;
}

// ---------------------------------------------------------------------------
// Kernel 2: feature cast/transpose NCHW f32 -> padded NHWC bf16 via LDS tile.
// ---------------------------------------------------------------------------
__global__ __launch_bounds__(256) void prep_feats(
    const float* __restrict__ f0, const float* __restrict__ f1,
    const float* __restrict__ f2, const float* __restrict__ f3,
    const float* __restrict__ f4, unsigned short* __restrict__ fpad)
{
    __shared__ unsigned short lds[64 * 258];
    int bi = blockIdx.x;            // < 3268
    int b = bi / 817;
    int r = bi - b * 817;
    const float* fsrc; int H, W, Wp, h, wb; long lb;
    if (r < 600)      { fsrc=f0; H=150; W=250; Wp=252; h=r>>2; wb=r&3; lb=32768    + (long)b*9805824; }
    else if (r < 750) { int rr=r-600; fsrc=f1; H=75; W=125; Wp=127; h=rr>>1; wb=rr&1; lb=39288832 + (long)b*2503424; }
    else if (r < 788) { fsrc=f2; H=38; W=63; Wp=65; h=r-750; wb=0; lb=49335296 + (long)b*665600; }
    else if (r < 807) { fsrc=f3; H=19; W=32; Wp=34; h=r-788; wb=0; lb=52030464 + (long)b*182784; }
    else              { fsrc=f4; H=10; W=16; Wp=18; h=r-807; wb=0; lb=52794368 + (long)b*55296; }
    const int t = threadIdx.x;
    const long cstr = (long)H * W;
    const int w = t & 63;
    const int wg = wb * 64 + w;
    const bool wv = (wg < W);
    const float* src = fsrc + (((long)b * 256) * H + h) * W + wg;
    unsigned* ldsw = (unsigned*)lds;
    #pragma unroll 4
    for (int it = 0; it < 32; ++it) {
        int c0 = (t >> 6) * 2 + it * 8;           // even c in [0,256)
        float v0 = wv ? src[(long)c0 * cstr] : 0.0f;
        float v1 = wv ? src[(long)(c0 + 1) * cstr] : 0.0f;
        unsigned pk = (unsigned)f2bf(v0) | ((unsigned)f2bf(v1) << 16);
        ldsw[w * 129 + (c0 >> 1)] = pk;
    }
    __syncthreads();
    #pragma unroll
    for (int k = 0; k < 8; ++k) {
        int g  = k * 256 + t;
        int px = g >> 5;                          // 0..63
        int pg = wb * 64 + px;
        if (pg >= W) continue;
        int d0 = px * 129 + (g & 31) * 4;         // dword index in lds
        uint4 v;
        v.x = ldsw[d0]; v.y = ldsw[d0 + 1]; v.z = ldsw[d0 + 2]; v.w = ldsw[d0 + 3];
        unsigned short* dst = fpad + lb + (long)((h + 1) * Wp + (pg + 1)) * 256 + (g & 31) * 8;
        *(uint4*)dst = v;
    }
}

// ---------------------------------------------------------------------------
// Kernel 3: main implicit-GEMM conv + fused head projection.
// 256^2 tile, 512 thr (8 waves: wm=wv&1 over M-halves, wn=wv>>1 over N-quads),
// BK=64, K = 9 taps x 4 channel-chunks = 36 K-tiles.
// LDS (128 KiB): buf{0,1} x { A[2 halves][128x64], B[2 halves][128x64] }.
// Per K-tile, 2 free-run regions split by 2 raw s_barriers (no lgkm drains):
//   R1: STAGE_A(t+1,h0/h1) -> rd af0-3,bfr0-3 -> Q1+Q2 MFMA   | SBAR(i)
//   R2: STAGE_B(t+2,h0/h1) -> rd af4-7        -> Q3+Q4 MFMA
//       vmcnt(4) | SBAR(ii) -> flip
// (i): B-reads implied-drained by Q2 operand waits; STAGE_B overwrites buf B.
// (ii): af4-7 drained by Q3/Q4; vmcnt(4) leaves only B(t+2) in flight.
// Grid 1600 = 800 tiles x 2 o-chunks; bijective XCD swizzle (1600%8==0).
// ---------------------------------------------------------------------------
__global__ __launch_bounds__(512) void conv_main(
    const unsigned short* __restrict__ fpad,
    const unsigned short* __restrict__ wr2,
    const unsigned short* __restrict__ wh2,
    const float* __restrict__ b_conv,
    float* __restrict__ sbuf)
{
    __shared__ __align__(16) char smem[131072];
    const int tid = threadIdx.x;
    const int bid = blockIdx.x;
    // XCD swizzle: swz consecutive within an XCD; tile's 2 chunks adjacent.
    const int swz = (bid & 7) * 200 + (bid >> 3);
    const int tile = swz >> 1;
    const int chunk = swz & 1;
    const int b = tile / 200;
    const int tr = tile - b * 200;
    int Wp, lt, ot, rowlim = 256; long lb;
    if (tr < 148)      { lt = tr;       Wp = 252; lb = 32768    + (long)b * 9805824; ot = b*399 + 2*lt; }
    else if (tr < 186) { lt = tr - 148; Wp = 127; lb = 39288832 + (long)b * 2503424; ot = b*399 + 296 + 2*lt;
                         if (lt == 37) rowlim = 128; }   // L1 has 75 old tiles: last super-tile is half
    else if (tr < 196) { lt = tr - 186; Wp = 65;  lb = 49335296 + (long)b * 665600;  ot = b*399 + 371 + 2*lt; }
    else if (tr < 199) { lt = tr - 196; Wp = 34;  lb = 52030464 + (long)b * 182784;  ot = b*399 + 391 + 2*lt; }
    else               { lt = 0;        Wp = 18;  lb = 52794368 + (long)b * 55296;   ot = b*399 + 397; }

    const int wv = tid >> 6, lane = tid & 63;
    // --- staging addressing: lane covers (row = wv*8 + i*64 + srow, 16B slot gslot)
    const int srow  = lane >> 3;                      // 0..7
    const int gslot = (lane & 7) ^ srow;              // pre-swizzled global slot
    const unsigned short* aBase = fpad + lb + (long)(Wp + lt*256 + wv*8 + srow) * 256 + gslot*8;
    const unsigned short* bBase = wr2 + (long)(chunk*256 + wv*8 + srow) * 2304 + gslot*8;

    // --- compute-side addressing
    const int wm = wv & 1, wn = wv >> 1;              // M-half, N-quad
    const int mr = lane & 15, kq4 = lane >> 4;        // frag row, k-quad
    const int m7 = mr & 7;
    const int aRd = wm * 16384 + mr * 128;                              // A half base + row
    const int bRd = 32768 + (wn >> 1) * 16384 + ((wn & 1) * 64 + mr) * 128;  // B half base + row
    const int sw0 = ((kq4 ^ m7) << 4);                // kk=0 swizzled slot byte
    const int sw1 = (((4 + kq4) ^ m7) << 4);          // kk=1

#define RD_A(bo_, mt_, sw_) (*(const bf16x8*)(smem + (bo_) + aRd + (mt_)*2048 + (sw_)))
#define RD_B(bo_, nt_, sw_) (*(const bf16x8*)(smem + (bo_) + bRd + (nt_)*2048 + (sw_)))

#define STAGE_A(bo_, kt_, h_) do {                                            \
        const int r_ = (kt_) >> 2;                                            \
        const int doff_ = (r_ / 3 - 1) * Wp + (r_ % 3 - 1);                   \
        const unsigned short* g_ = aBase + ((long)((h_) * 128 + doff_)) * 256 \
                                   + ((kt_) & 3) * 64;                        \
        char* l_ = smem + (bo_) + (h_) * 16384 + wv * 1024;                   \
        gl_lds16(g_,          l_);                                            \
        gl_lds16(g_ + 16384,  l_ + 8192);                                     \
    } while (0)

#define STAGE_B(bo_, kt_, h_) do {                                            \
        const unsigned short* g_ = bBase + (long)(h_) * 294912 + (kt_) * 64;  \
        char* l_ = smem + (bo_) + 32768 + (h_) * 16384 + wv * 1024;           \
        gl_lds16(g_,           l_);                                           \
        gl_lds16(g_ + 147456,  l_ + 8192);                                    \
    } while (0)

#define MFMA16(d_, a_, b_) d_ = __builtin_amdgcn_mfma_f32_16x16x32_bf16(a_, b_, d_, 0, 0, 0)
#define SBAR   do { asm volatile("s_barrier" ::: "memory"); \
                    __builtin_amdgcn_sched_barrier(0); } while (0)

    f32x4 acc[8][4];
    #pragma unroll
    for (int mt = 0; mt < 8; ++mt)
        #pragma unroll
        for (int nt = 0; nt < 4; ++nt) acc[mt][nt] = (f32x4){0.f, 0.f, 0.f, 0.f};

    // Prologue: K0 fully + B(1) in flight; vmcnt(4) leaves only B(1) outstanding.
    STAGE_A(0, 0, 0); STAGE_A(0, 0, 1);
    STAGE_B(0, 0, 0); STAGE_B(0, 0, 1);
    STAGE_B(65536, 1, 0); STAGE_B(65536, 1, 1);
    asm volatile("s_waitcnt vmcnt(4)" ::: "memory");
    SBAR;

    bf16x8 af[4][2], bfr[4][2];
    #pragma unroll 2
    for (int t = 0; t < 36; ++t) {
        const int bo  = (t & 1) << 16;
        const int bon = bo ^ 65536;

        // ---- Region 1: stage A(t+1) both halves, read af0-3 + bfr0-3, Q1+Q2.
        if (t < 35) { STAGE_A(bon, t + 1, 0); STAGE_A(bon, t + 1, 1); }
        #pragma unroll
        for (int mt = 0; mt < 4; ++mt) { af[mt][0] = RD_A(bo, mt, sw0); af[mt][1] = RD_A(bo, mt, sw1); }
        #pragma unroll
        for (int nt = 0; nt < 4; ++nt) { bfr[nt][0] = RD_B(bo, nt, sw0); bfr[nt][1] = RD_B(bo, nt, sw1); }
        __builtin_amdgcn_s_setprio(1);
        #pragma unroll
        for (int mt = 0; mt < 4; ++mt)
            #pragma unroll
            for (int nt = 0; nt < 4; ++nt) {
                MFMA16(acc[mt][nt], af[mt][0], bfr[nt][0]);
                MFMA16(acc[mt][nt], af[mt][1], bfr[nt][1]);
            }
        __builtin_amdgcn_s_setprio(0);
        SBAR;   // (i): every wave's B-reads consumed -> B slots of buf are dead

        // ---- Region 2: stage B(t+2) into current buf, read af4-7, Q3+Q4.
        if (t < 34) { STAGE_B(bo, t + 2, 0); STAGE_B(bo, t + 2, 1); }
        #pragma unroll
        for (int mt = 0; mt < 4; ++mt) { af[mt][0] = RD_A(bo, mt + 4, sw0); af[mt][1] = RD_A(bo, mt + 4, sw1); }
        __builtin_amdgcn_s_setprio(1);
        #pragma unroll
        for (int mt = 0; mt < 4; ++mt)
            #pragma unroll
            for (int nt = 0; nt < 4; ++nt) {
                MFMA16(acc[mt + 4][nt], af[mt][0], bfr[nt][0]);
                MFMA16(acc[mt + 4][nt], af[mt][1], bfr[nt][1]);
            }
        __builtin_amdgcn_s_setprio(0);
        if (t < 34) { asm volatile("s_waitcnt vmcnt(4)" ::: "memory"); }
        else        { asm volatile("s_waitcnt vmcnt(0)" ::: "memory"); }
        SBAR;   // (ii): staging landed everywhere; flip buffers
    }

    // Epilogue: bias + relu, conv1 -> LDS bf16 [256 px][256 o], XOR-swizzled slots.
    float bias[4];
    const int ncol = wn * 64;
    #pragma unroll
    for (int nt = 0; nt < 4; ++nt) bias[nt] = b_conv[chunk * 256 + ncol + nt * 16 + mr];
    #pragma unroll
    for (int mt = 0; mt < 8; ++mt)
        #pragma unroll
        for (int nt = 0; nt < 4; ++nt)
            #pragma unroll
            for (int q = 0; q < 4; ++q) {
                int row = wm * 128 + mt * 16 + kq4 * 4 + q;
                int col = ncol + nt * 16 + mr;
                int sl  = (col >> 3) ^ (row & 7);
                *(unsigned short*)(smem + row * 512 + (sl << 4) + ((col & 7) << 1)) =
                    f2bf(fmaxf(acc[mt][nt][q] + bias[nt], 0.0f));
            }
    __syncthreads();

    // Head GEMM: each wave does 32 px rows x 32 j over K=256 (this chunk's o).
    f32x4 acc2[2][2];
    #pragma unroll
    for (int mi = 0; mi < 2; ++mi)
        #pragma unroll
        for (int ni = 0; ni < 2; ++ni) acc2[mi][ni] = (f32x4){0.f, 0.f, 0.f, 0.f};
    const int hrow = wv * 32 + mr;
    #pragma unroll
    for (int ks = 0; ks < 8; ++ks) {
        const int swh = (((ks * 4 + kq4) ^ m7) << 4);
        bf16x8 ha0 = *(const bf16x8*)(smem + hrow * 512 + swh);
        bf16x8 ha1 = *(const bf16x8*)(smem + (hrow + 16) * 512 + swh);
        bf16x8 hb0 = *(const bf16x8*)&wh2[mr * 512 + chunk * 256 + ks * 32 + kq4 * 8];
        bf16x8 hb1 = *(const bf16x8*)&wh2[(16 + mr) * 512 + chunk * 256 + ks * 32 + kq4 * 8];
        MFMA16(acc2[0][0], ha0, hb0); MFMA16(acc2[0][1], ha0, hb1);
        MFMA16(acc2[1][0], ha1, hb0); MFMA16(acc2[1][1], ha1, hb1);
    }
    const long slotbase = (long)ot * 128;
    #pragma unroll
    for (int ni = 0; ni < 2; ++ni) {
        int j = ni * 16 + mr;
        if (j < 18) {
            #pragma unroll
            for (int mi = 0; mi < 2; ++mi)
                #pragma unroll
                for (int q = 0; q < 4; ++q) {
                    int row = wv * 32 + mi * 16 + kq4 * 4 + q;
                    if (row < rowlim)
                        atomicAdd(&sbuf[(slotbase + row) * 18 + j], acc2[mi][ni][q]);
                }
        }
    }
#undef RD_A
#undef RD_B
#undef STAGE_A
#undef STAGE_B
#undef MFMA16
#undef SBAR
}

// ---------------------------------------------------------------------------
// Kernel 4: finalize. slot -> (b,level,hp,wp); biases, paired sigmoid-softmax
// (partner = c +/- 3), scatter into the 3 concatenated outputs.
// ---------------------------------------------------------------------------
__global__ __launch_bounds__(256) void finalize(
    const float* __restrict__ sbuf, const float* __restrict__ b_cls,
    const float* __restrict__ b_box, float* __restrict__ out)
{
    int idx = blockIdx.x * 256 + threadIdx.x;      // < 204288
    int tile = idx >> 7, m = idx & 127;
    int b = tile / 399;
    int tr = tile - b * 399;
    int hp, wp, H, W, noff;
    if (tr < 296)      { int f = 252 + (tr)       * 128 + m; hp = f / 252; wp = f - hp * 252; H = 150; W = 250; noff = 0; }
    else if (tr < 371) { int f = 127 + (tr - 296) * 128 + m; hp = f / 127; wp = f - hp * 127; H = 75;  W = 125; noff = 112500; }
    else if (tr < 391) { int f = 65  + (tr - 371) * 128 + m; hp = f / 65;  wp = f - hp * 65;  H = 38;  W = 63;  noff = 140625; }
    else if (tr < 397) { int f = 34  + (tr - 391) * 128 + m; hp = f / 34;  wp = f - hp * 34;  H = 19;  W = 32;  noff = 147807; }
    else               { int f = 18  + (tr - 397) * 128 + m; hp = f / 18;  wp = f - hp * 18;  H = 10;  W = 16;  noff = 149631; }
    if (hp < 1 || hp > H || wp < 1 || wp > W) return;

    const float* s = sbuf + (long)idx * 18;
    float sc[6], bb[12], pr[6];
    #pragma unroll
    for (int c = 0; c < 6; ++c) sc[c] = s[c] + b_cls[c];
    #pragma unroll
    for (int k = 0; k < 12; ++k) bb[k] = s[6 + k] + b_box[k];
    #pragma unroll
    for (int c = 0; c < 6; ++c) {
        int p = (c < 3) ? c + 3 : c - 3;
        pr[c] = 1.0f / (1.0f + expf(sc[p] - sc[c]));
    }
    int n = noff + ((hp - 1) * W + (wp - 1)) * 3;
    long o0 = ((long)b * 150111 + n) * 2;
    float* O0 = out + o0;
    float* O1 = out + 1200888 + o0;
    float* O2 = out + 2401776 + ((long)b * 150111 + n) * 4;
    #pragma unroll
    for (int c = 0; c < 6; ++c) { O0[c] = sc[c]; O1[c] = pr[c]; }
    #pragma unroll
    for (int k = 0; k < 12; ++k) O2[k] = bb[k];
}

// ---------------------------------------------------------------------------
extern "C" void kernel_launch(void* const* d_in, const int* in_sizes, int n_in,
                              void* d_out, int out_size, void* d_ws, size_t ws_size,
                              hipStream_t stream)
{
    const float* f0   = (const float*)d_in[0];
    const float* f1   = (const float*)d_in[1];
    const float* f2   = (const float*)d_in[2];
    const float* f3   = (const float*)d_in[3];
    const float* f4   = (const float*)d_in[4];
    // d_in[5] = im_info (unused by reference math)
    const float* Wc   = (const float*)d_in[6];
    const float* bC   = (const float*)d_in[7];
    const float* Wcls = (const float*)d_in[8];
    const float* bcls = (const float*)d_in[9];
    const float* Wbox = (const float*)d_in[10];
    const float* bbox = (const float*)d_in[11];

    unsigned short* wr2  = (unsigned short*)((char*)d_ws + WS_WR2_OFF);
    unsigned short* wh2  = (unsigned short*)((char*)d_ws + WS_WH2_OFF);
    float*          sbuf = (float*)((char*)d_ws + WS_SB_OFF);
    unsigned short* fpad = (unsigned short*)((char*)d_ws + WS_FP_OFF);

    // Zero only what correctness needs: sbuf (atomic init) + pad rings + wh2 tail.
    hipMemsetAsync((char*)d_ws + WS_SB_OFF, 0, (size_t)(WS_FP_OFF - WS_SB_OFF), stream);
    hipLaunchKernelGGL(prep_weights, dim3(4672), dim3(256), 0, stream, Wc, Wcls, Wbox, wr2, wh2);
    hipLaunchKernelGGL(zero_rings,   dim3(788),  dim3(256), 0, stream, fpad);
    hipLaunchKernelGGL(prep_feats,   dim3(3268), dim3(256), 0, stream, f0, f1, f2, f3, f4, fpad);
    hipLaunchKernelGGL(conv_main,    dim3(1600), dim3(512), 0, stream, fpad, wr2, wh2, bC, sbuf);
    hipLaunchKernelGGL(finalize,     dim3(798),  dim3(256), 0, stream, sbuf, bcls, bbox, (float*)d_out);
}

// Round 4
// 745.528 us; speedup vs baseline: 1.0401x; 1.0401x over previous
//
#include <hip/hip_runtime.h>
#include <stdint.h>

// ---------------------------------------------------------------------------
// RPN FPN head, MI355X (gfx950).
// conv3x3(256->512)+ReLU as implicit GEMM, 256^2 tile / 512 thr / 8 waves,
// BK=64, double-buffered 128 KiB LDS, R2 schedule (measured best, 469us):
// 4 drained phases per K-tile, 2 raw s_barriers. Barrier (i) gates
// STAGE_B(t+2) vs all waves' B-reads; barrier (ii) gates the buffer flip
// after counted vmcnt(4). setprio(1) around MFMA clusters, XOR-swizzled LDS
// slots, bijective XCD grid swizzle. Fused 1x1 heads via small MFMA +
// atomicAdd partials; finalize does biases + paired softmax.
// All prep work (feat transpose, weight repack, pad-ring zero, sbuf zero)
// is fused into ONE kernel (prep_all) -> 3 dispatches total.
//
// Workspace layout (bytes):
//   [0,        2359296)   Wr2  bf16 [512 o][2304 k]   (B^T conv weights, k=(kh,kw,c))
//   [2359296,  2392064)   Wh2  bf16 [32 j][512 o]     (cls 0..5, box 6..17, 18..31 zero)
//   [2392064, 17100800)   sbuf f32  [204288 slot][18] (head partial sums; zeroed in prep_all)
//   [17100800,123197440)  fpad bf16 padded NHWC feats (only pad RINGS zeroed;
//                         guard/overrun cells may hold poison -> outputs discarded)
// ---------------------------------------------------------------------------

typedef __bf16 bf16x8 __attribute__((ext_vector_type(8)));
typedef float  f32x4  __attribute__((ext_vector_type(4)));

#define WS_WR2_OFF   0
#define WS_WH2_OFF   2359296
#define WS_SB_OFF    2392064
#define WS_FP_OFF    17100800
#define WS_TOTAL     123197440

__device__ __forceinline__ unsigned short f2bf(float f) {
    unsigned u = __builtin_bit_cast(unsigned, f);
    unsigned r = (u + 0x7FFF + ((u >> 16) & 1)) >> 16;
    return (unsigned short)r;
}

__device__ __forceinline__ void gl_lds16(const void* g, void* l) {
    __builtin_amdgcn_global_load_lds(
        (const __attribute__((address_space(1))) unsigned int*)g,
        (__attribute__((address_space(3))) unsigned int*)l, 16, 0, 0);
}

// ---------------------------------------------------------------------------
// Kernel 1: fused prep. Block ranges (longest work first for packing):
//   [0, 3268)      : feature cast/transpose NCHW f32 -> padded NHWC bf16
//   [3268, 7940)   : weight repack (conv B^T + head Wh2)
//   [7940, 8728)   : zero SAME-padding rings of fpad
//   [8728, 12319)  : zero sbuf (replaces hipMemsetAsync)
// All four jobs are independent; conv_main depends on all -> stream order.
// ---------------------------------------------------------------------------
__global__ __launch_bounds__(256) void prep_all(
    const float* __restrict__ f0, const float* __restrict__ f1,
    const float* __restrict__ f2, const float* __restrict__ f3,
    const float* __restrict__ f4,
    const float* __restrict__ Wc, const float* __restrict__ Wcls,
    const float* __restrict__ Wbox,
    unsigned short* __restrict__ wr2, unsigned short* __restrict__ wh2,
    unsigned short* __restrict__ fpad, float* __restrict__ sbuf)
{
    __shared__ unsigned short lds[64 * 258];
    const int blk = blockIdx.x;
    const int t = threadIdx.x;

    if (blk < 3268) {
        // ---- feature transpose ----
        int bi = blk;
        int b = bi / 817;
        int r = bi - b * 817;
        const float* fsrc; int H, W, Wp, h, wb; long lb;
        if (r < 600)      { fsrc=f0; H=150; W=250; Wp=252; h=r>>2; wb=r&3; lb=32768    + (long)b*9805824; }
        else if (r < 750) { int rr=r-600; fsrc=f1; H=75; W=125; Wp=127; h=rr>>1; wb=rr&1; lb=39288832 + (long)b*2503424; }
        else if (r < 788) { fsrc=f2; H=38; W=63; Wp=65; h=r-750; wb=0; lb=49335296 + (long)b*665600; }
        else if (r < 807) { fsrc=f3; H=19; W=32; Wp=34; h=r-788; wb=0; lb=52030464 + (long)b*182784; }
        else              { fsrc=f4; H=10; W=16; Wp=18; h=r-807; wb=0; lb=52794368 + (long)b*55296; }
        const long cstr = (long)H * W;
        const int w = t & 63;
        const int wg = wb * 64 + w;
        const bool wv = (wg < W);
        const float* src = fsrc + (((long)b * 256) * H + h) * W + wg;
        unsigned* ldsw = (unsigned*)lds;
        #pragma unroll 4
        for (int it = 0; it < 32; ++it) {
            int c0 = (t >> 6) * 2 + it * 8;           // even c in [0,256)
            float v0 = wv ? src[(long)c0 * cstr] : 0.0f;
            float v1 = wv ? src[(long)(c0 + 1) * cstr] : 0.0f;
            unsigned pk = (unsigned)f2bf(v0) | ((unsigned)f2bf(v1) << 16);
            ldsw[w * 129 + (c0 >> 1)] = pk;
        }
        __syncthreads();
        #pragma unroll
        for (int k = 0; k < 8; ++k) {
            int g  = k * 256 + t;
            int px = g >> 5;                          // 0..63
            int pg = wb * 64 + px;
            if (pg >= W) continue;
            int d0 = px * 129 + (g & 31) * 4;         // dword index in lds
            uint4 v;
            v.x = ldsw[d0]; v.y = ldsw[d0 + 1]; v.z = ldsw[d0 + 2]; v.w = ldsw[d0 + 3];
            unsigned short* dst = fpad + lb + (long)((h + 1) * Wp + (pg + 1)) * 256 + (g & 31) * 8;
            *(uint4*)dst = v;
        }
    } else if (blk < 7940) {
        // ---- weight repack ----
        int idx = (blk - 3268) * 256 + t;
        if (idx < 1179648) {
            int o = idx / 2304;
            int k = idx - o * 2304;
            int r = k >> 8, c = k & 255;
            wr2[idx] = f2bf(Wc[o * 2304 + c * 9 + r]);
        } else {
            int i2 = idx - 1179648;
            if (i2 < 16384) {
                int j = i2 >> 9, o = i2 & 511;
                float v = (j < 6) ? Wcls[j * 512 + o]
                        : (j < 18) ? Wbox[(j - 6) * 512 + o] : 0.0f;
                wh2[j * 512 + o] = f2bf(v);
            }
        }
    } else if (blk < 8728) {
        // ---- zero pad rings ----
        int idx = (blk - 7940) * 256 + t;            // < 201728 = 4 * 50432
        int b = idx / 50432;
        int rem = idx - b * 50432;
        int Wp, H, W; long lb;
        if (rem < 25728)      {               Wp=252; H=150; W=250; lb=32768    + (long)b*9805824; }
        else if (rem < 38656) { rem -= 25728; Wp=127; H=75;  W=125; lb=39288832 + (long)b*2503424; }
        else if (rem < 45248) { rem -= 38656; Wp=65;  H=38;  W=63;  lb=49335296 + (long)b*665600;  }
        else if (rem < 48640) { rem -= 45248; Wp=34;  H=19;  W=32;  lb=52030464 + (long)b*182784;  }
        else                  { rem -= 48640; Wp=18;  H=10;  W=16;  lb=52794368 + (long)b*55296;   }
        int c = rem >> 5, slot = rem & 31;
        int h, w;
        if (c < Wp)          { h = 0;     w = c; }
        else if (c < 2 * Wp) { h = H + 1; w = c - Wp; }
        else {
            int c2 = c - 2 * Wp;
            h = 1 + (c2 >> 1);
            w = (c2 & 1) ? (W + 1) : 0;
        }
        uint4 z = {0u, 0u, 0u, 0u};
        *(uint4*)(fpad + lb + (long)(h * Wp + w) * 256 + slot * 8) = z;
    } else {
        // ---- zero sbuf: 14708736 B = 919296 uint4 = 3591 blocks * 256 ----
        int idx = (blk - 8728) * 256 + t;
        uint4 z = {0u, 0u, 0u, 0u};
        ((uint4*)sbuf)[idx] = z;
    }
}

// ---------------------------------------------------------------------------
// Kernel 2: main implicit-GEMM conv + fused head projection.  (R2 schedule)
// 256^2 tile, 512 thr (8 waves: wm=wv&1 over M-halves, wn=wv>>1 over N-quads),
// BK=64, K = 9 taps x 4 channel-chunks = 36 K-tiles.
// LDS (128 KiB): buf{0,1} x { A[2 halves][128x64], B[2 halves][128x64] }.
// Phases (each: reads, stage, own lgkmcnt(0) drain, MFMA burst):
//   ph1: rd af0-3,bfr0-1 (12), STAGE_A(t+1,h0), lgkm0, Q1(m0-3,n0-1)
//   ph2: rd bfr2-3 (4),        STAGE_A(t+1,h1), lgkm0, SBAR(i), Q2
//   ph3: rd af4-7 (8),         STAGE_B(t+2,h0), lgkm0, Q3(m4-7,n0-1)
//   ph4:                       STAGE_B(t+2,h1), Q4, vmcnt(4), SBAR(ii)
// (i) = all waves' B-reads drained  -> STAGE_B may overwrite current buf B.
// (ii) = all waves' staging landed + A-reads drained -> flip buffers.
// Grid 1600 = 800 tiles x 2 o-chunks; bijective XCD swizzle (1600%8==0).
// ---------------------------------------------------------------------------
__global__ __launch_bounds__(512) void conv_main(
    const unsigned short* __restrict__ fpad,
    const unsigned short* __restrict__ wr2,
    const unsigned short* __restrict__ wh2,
    const float* __restrict__ b_conv,
    float* __restrict__ sbuf)
{
    __shared__ __align__(16) char smem[131072];
    const int tid = threadIdx.x;
    const int bid = blockIdx.x;
    // XCD swizzle: swz consecutive within an XCD; tile's 2 chunks adjacent.
    const int swz = (bid & 7) * 200 + (bid >> 3);
    const int tile = swz >> 1;
    const int chunk = swz & 1;
    const int b = tile / 200;
    const int tr = tile - b * 200;
    int Wp, lt, ot, rowlim = 256; long lb;
    if (tr < 148)      { lt = tr;       Wp = 252; lb = 32768    + (long)b * 9805824; ot = b*399 + 2*lt; }
    else if (tr < 186) { lt = tr - 148; Wp = 127; lb = 39288832 + (long)b * 2503424; ot = b*399 + 296 + 2*lt;
                         if (lt == 37) rowlim = 128; }   // L1 has 75 old tiles: last super-tile is half
    else if (tr < 196) { lt = tr - 186; Wp = 65;  lb = 49335296 + (long)b * 665600;  ot = b*399 + 371 + 2*lt; }
    else if (tr < 199) { lt = tr - 196; Wp = 34;  lb = 52030464 + (long)b * 182784;  ot = b*399 + 391 + 2*lt; }
    else               { lt = 0;        Wp = 18;  lb = 52794368 + (long)b * 55296;   ot = b*399 + 397; }

    const int wv = tid >> 6, lane = tid & 63;
    // --- staging addressing: lane covers (row = wv*8 + i*64 + srow, 16B slot gslot)
    const int srow  = lane >> 3;                      // 0..7
    const int gslot = (lane & 7) ^ srow;              // pre-swizzled global slot
    const unsigned short* aBase = fpad + lb + (long)(Wp + lt*256 + wv*8 + srow) * 256 + gslot*8;
    const unsigned short* bBase = wr2 + (long)(chunk*256 + wv*8 + srow) * 2304 + gslot*8;

    // --- compute-side addressing
    const int wm = wv & 1, wn = wv >> 1;              // M-half, N-quad
    const int mr = lane & 15, kq4 = lane >> 4;        // frag row, k-quad
    const int m7 = mr & 7;
    const int aRd = wm * 16384 + mr * 128;                              // A half base + row
    const int bRd = 32768 + (wn >> 1) * 16384 + ((wn & 1) * 64 + mr) * 128;  // B half base + row
    const int sw0 = ((kq4 ^ m7) << 4);                // kk=0 swizzled slot byte
    const int sw1 = (((4 + kq4) ^ m7) << 4);          // kk=1

#define RD_A(bo_, mt_, sw_) (*(const bf16x8*)(smem + (bo_) + aRd + (mt_)*2048 + (sw_)))
#define RD_B(bo_, nt_, sw_) (*(const bf16x8*)(smem + (bo_) + bRd + (nt_)*2048 + (sw_)))

#define STAGE_A(bo_, kt_, h_) do {                                            \
        const int r_ = (kt_) >> 2;                                            \
        const int doff_ = (r_ / 3 - 1) * Wp + (r_ % 3 - 1);                   \
        const unsigned short* g_ = aBase + ((long)((h_) * 128 + doff_)) * 256 \
                                   + ((kt_) & 3) * 64;                        \
        char* l_ = smem + (bo_) + (h_) * 16384 + wv * 1024;                   \
        gl_lds16(g_,          l_);                                            \
        gl_lds16(g_ + 16384,  l_ + 8192);                                     \
    } while (0)

#define STAGE_B(bo_, kt_, h_) do {                                            \
        const unsigned short* g_ = bBase + (long)(h_) * 294912 + (kt_) * 64;  \
        char* l_ = smem + (bo_) + 32768 + (h_) * 16384 + wv * 1024;           \
        gl_lds16(g_,           l_);                                           \
        gl_lds16(g_ + 147456,  l_ + 8192);                                    \
    } while (0)

#define MFMA16(d_, a_, b_) d_ = __builtin_amdgcn_mfma_f32_16x16x32_bf16(a_, b_, d_, 0, 0, 0)
#define LGKM0  do { asm volatile("s_waitcnt lgkmcnt(0)" ::: "memory"); \
                    __builtin_amdgcn_sched_barrier(0); } while (0)
#define SBAR   do { asm volatile("s_barrier" ::: "memory"); \
                    __builtin_amdgcn_sched_barrier(0); } while (0)

    f32x4 acc[8][4];
    #pragma unroll
    for (int mt = 0; mt < 8; ++mt)
        #pragma unroll
        for (int nt = 0; nt < 4; ++nt) acc[mt][nt] = (f32x4){0.f, 0.f, 0.f, 0.f};

    // Prologue: K0 fully + B(1) in flight; vmcnt(4) leaves only B(1) outstanding.
    STAGE_A(0, 0, 0); STAGE_A(0, 0, 1);
    STAGE_B(0, 0, 0); STAGE_B(0, 0, 1);
    STAGE_B(65536, 1, 0); STAGE_B(65536, 1, 1);
    asm volatile("s_waitcnt vmcnt(4)" ::: "memory");
    __builtin_amdgcn_s_barrier();

    bf16x8 af[4][2], bfr[4][2];
    #pragma unroll 2
    for (int t = 0; t < 36; ++t) {
        const int bo  = (t & 1) << 16;
        const int bon = bo ^ 65536;

        // ---- ph1: read A0-3 + B0-1, stage A(t+1,h0), MFMA Q1 (m0-3 x n0-1)
        #pragma unroll
        for (int mt = 0; mt < 4; ++mt) { af[mt][0] = RD_A(bo, mt, sw0); af[mt][1] = RD_A(bo, mt, sw1); }
        #pragma unroll
        for (int nt = 0; nt < 2; ++nt) { bfr[nt][0] = RD_B(bo, nt, sw0); bfr[nt][1] = RD_B(bo, nt, sw1); }
        if (t < 35) STAGE_A(bon, t + 1, 0);
        LGKM0;
        __builtin_amdgcn_s_setprio(1);
        #pragma unroll
        for (int mt = 0; mt < 4; ++mt)
            #pragma unroll
            for (int nt = 0; nt < 2; ++nt) {
                MFMA16(acc[mt][nt], af[mt][0], bfr[nt][0]);
                MFMA16(acc[mt][nt], af[mt][1], bfr[nt][1]);
            }
        __builtin_amdgcn_s_setprio(0);
        __builtin_amdgcn_sched_barrier(0);

        // ---- ph2: read B2-3, stage A(t+1,h1), BARRIER(i), MFMA Q2 (m0-3 x n2-3)
        #pragma unroll
        for (int nt = 2; nt < 4; ++nt) { bfr[nt][0] = RD_B(bo, nt, sw0); bfr[nt][1] = RD_B(bo, nt, sw1); }
        if (t < 35) STAGE_A(bon, t + 1, 1);
        LGKM0;
        SBAR;                      // (i): every wave's B-reads are complete
        __builtin_amdgcn_s_setprio(1);
        #pragma unroll
        for (int mt = 0; mt < 4; ++mt)
            #pragma unroll
            for (int nt = 2; nt < 4; ++nt) {
                MFMA16(acc[mt][nt], af[mt][0], bfr[nt][0]);
                MFMA16(acc[mt][nt], af[mt][1], bfr[nt][1]);
            }
        __builtin_amdgcn_s_setprio(0);
        __builtin_amdgcn_sched_barrier(0);

        // ---- ph3: read A4-7, stage B(t+2,h0) into current buf (B now dead), MFMA Q3
        #pragma unroll
        for (int mt = 0; mt < 4; ++mt) { af[mt][0] = RD_A(bo, mt + 4, sw0); af[mt][1] = RD_A(bo, mt + 4, sw1); }
        if (t < 34) STAGE_B(bo, t + 2, 0);
        LGKM0;
        __builtin_amdgcn_s_setprio(1);
        #pragma unroll
        for (int mt = 0; mt < 4; ++mt)
            #pragma unroll
            for (int nt = 0; nt < 2; ++nt) {
                MFMA16(acc[mt + 4][nt], af[mt][0], bfr[nt][0]);
                MFMA16(acc[mt + 4][nt], af[mt][1], bfr[nt][1]);
            }
        __builtin_amdgcn_s_setprio(0);
        __builtin_amdgcn_sched_barrier(0);

        // ---- ph4: stage B(t+2,h1), MFMA Q4, counted vmcnt, BARRIER(ii), flip
        if (t < 34) STAGE_B(bo, t + 2, 1);
        __builtin_amdgcn_s_setprio(1);
        #pragma unroll
        for (int mt = 0; mt < 4; ++mt)
            #pragma unroll
            for (int nt = 2; nt < 4; ++nt) {
                MFMA16(acc[mt + 4][nt], af[mt][0], bfr[nt][0]);
                MFMA16(acc[mt + 4][nt], af[mt][1], bfr[nt][1]);
            }
        __builtin_amdgcn_s_setprio(0);
        __builtin_amdgcn_sched_barrier(0);
        if (t < 34) { asm volatile("s_waitcnt vmcnt(4)" ::: "memory"); }
        else        { asm volatile("s_waitcnt vmcnt(0)" ::: "memory"); }
        SBAR;                      // (ii): staging landed everywhere; flip buffers
    }

    // Epilogue: bias + relu, conv1 -> LDS bf16 [256 px][256 o], XOR-swizzled slots.
    float bias[4];
    const int ncol = wn * 64;
    #pragma unroll
    for (int nt = 0; nt < 4; ++nt) bias[nt] = b_conv[chunk * 256 + ncol + nt * 16 + mr];
    #pragma unroll
    for (int mt = 0; mt < 8; ++mt)
        #pragma unroll
        for (int nt = 0; nt < 4; ++nt)
            #pragma unroll
            for (int q = 0; q < 4; ++q) {
                int row = wm * 128 + mt * 16 + kq4 * 4 + q;
                int col = ncol + nt * 16 + mr;
                int sl  = (col >> 3) ^ (row & 7);
                *(unsigned short*)(smem + row * 512 + (sl << 4) + ((col & 7) << 1)) =
                    f2bf(fmaxf(acc[mt][nt][q] + bias[nt], 0.0f));
            }
    __syncthreads();

    // Head GEMM: each wave does 32 px rows x 32 j over K=256 (this chunk's o).
    f32x4 acc2[2][2];
    #pragma unroll
    for (int mi = 0; mi < 2; ++mi)
        #pragma unroll
        for (int ni = 0; ni < 2; ++ni) acc2[mi][ni] = (f32x4){0.f, 0.f, 0.f, 0.f};
    const int hrow = wv * 32 + mr;
    #pragma unroll
    for (int ks = 0; ks < 8; ++ks) {
        const int swh = (((ks * 4 + kq4) ^ m7) << 4);
        bf16x8 ha0 = *(const bf16x8*)(smem + hrow * 512 + swh);
        bf16x8 ha1 = *(const bf16x8*)(smem + (hrow + 16) * 512 + swh);
        bf16x8 hb0 = *(const bf16x8*)&wh2[mr * 512 + chunk * 256 + ks * 32 + kq4 * 8];
        bf16x8 hb1 = *(const bf16x8*)&wh2[(16 + mr) * 512 + chunk * 256 + ks * 32 + kq4 * 8];
        MFMA16(acc2[0][0], ha0, hb0); MFMA16(acc2[0][1], ha0, hb1);
        MFMA16(acc2[1][0], ha1, hb0); MFMA16(acc2[1][1], ha1, hb1);
    }
    const long slotbase = (long)ot * 128;
    #pragma unroll
    for (int ni = 0; ni < 2; ++ni) {
        int j = ni * 16 + mr;
        if (j < 18) {
            #pragma unroll
            for (int mi = 0; mi < 2; ++mi)
                #pragma unroll
                for (int q = 0; q < 4; ++q) {
                    int row = wv * 32 + mi * 16 + kq4 * 4 + q;
                    if (row < rowlim)
                        atomicAdd(&sbuf[(slotbase + row) * 18 + j], acc2[mi][ni][q]);
                }
        }
    }
#undef RD_A
#undef RD_B
#undef STAGE_A
#undef STAGE_B
#undef MFMA16
#undef LGKM0
#undef SBAR
}

// ---------------------------------------------------------------------------
// Kernel 3: finalize. slot -> (b,level,hp,wp); biases, paired sigmoid-softmax
// (partner = c +/- 3), scatter into the 3 concatenated outputs.
// ---------------------------------------------------------------------------
__global__ __launch_bounds__(256) void finalize(
    const float* __restrict__ sbuf, const float* __restrict__ b_cls,
    const float* __restrict__ b_box, float* __restrict__ out)
{
    int idx = blockIdx.x * 256 + threadIdx.x;      // < 204288
    int tile = idx >> 7, m = idx & 127;
    int b = tile / 399;
    int tr = tile - b * 399;
    int hp, wp, H, W, noff;
    if (tr < 296)      { int f = 252 + (tr)       * 128 + m; hp = f / 252; wp = f - hp * 252; H = 150; W = 250; noff = 0; }
    else if (tr < 371) { int f = 127 + (tr - 296) * 128 + m; hp = f / 127; wp = f - hp * 127; H = 75;  W = 125; noff = 112500; }
    else if (tr < 391) { int f = 65  + (tr - 371) * 128 + m; hp = f / 65;  wp = f - hp * 65;  H = 38;  W = 63;  noff = 140625; }
    else if (tr < 397) { int f = 34  + (tr - 391) * 128 + m; hp = f / 34;  wp = f - hp * 34;  H = 19;  W = 32;  noff = 147807; }
    else               { int f = 18  + (tr - 397) * 128 + m; hp = f / 18;  wp = f - hp * 18;  H = 10;  W = 16;  noff = 149631; }
    if (hp < 1 || hp > H || wp < 1 || wp > W) return;

    const float* s = sbuf + (long)idx * 18;
    float sc[6], bb[12], pr[6];
    #pragma unroll
    for (int c = 0; c < 6; ++c) sc[c] = s[c] + b_cls[c];
    #pragma unroll
    for (int k = 0; k < 12; ++k) bb[k] = s[6 + k] + b_box[k];
    #pragma unroll
    for (int c = 0; c < 6; ++c) {
        int p = (c < 3) ? c + 3 : c - 3;
        pr[c] = 1.0f / (1.0f + expf(sc[p] - sc[c]));
    }
    int n = noff + ((hp - 1) * W + (wp - 1)) * 3;
    long o0 = ((long)b * 150111 + n) * 2;
    float* O0 = out + o0;
    float* O1 = out + 1200888 + o0;
    float* O2 = out + 2401776 + ((long)b * 150111 + n) * 4;
    #pragma unroll
    for (int c = 0; c < 6; ++c) { O0[c] = sc[c]; O1[c] = pr[c]; }
    #pragma unroll
    for (int k = 0; k < 12; ++k) O2[k] = bb[k];
}

// ---------------------------------------------------------------------------
extern "C" void kernel_launch(void* const* d_in, const int* in_sizes, int n_in,
                              void* d_out, int out_size, void* d_ws, size_t ws_size,
                              hipStream_t stream)
{
    const float* f0   = (const float*)d_in[0];
    const float* f1   = (const float*)d_in[1];
    const float* f2   = (const float*)d_in[2];
    const float* f3   = (const float*)d_in[3];
    const float* f4   = (const float*)d_in[4];
    // d_in[5] = im_info (unused by reference math)
    const float* Wc   = (const float*)d_in[6];
    const float* bC   = (const float*)d_in[7];
    const float* Wcls = (const float*)d_in[8];
    const float* bcls = (const float*)d_in[9];
    const float* Wbox = (const float*)d_in[10];
    const float* bbox = (const float*)d_in[11];

    unsigned short* wr2  = (unsigned short*)((char*)d_ws + WS_WR2_OFF);
    unsigned short* wh2  = (unsigned short*)((char*)d_ws + WS_WH2_OFF);
    float*          sbuf = (float*)((char*)d_ws + WS_SB_OFF);
    unsigned short* fpad = (unsigned short*)((char*)d_ws + WS_FP_OFF);

    hipLaunchKernelGGL(prep_all,  dim3(12319), dim3(256), 0, stream,
                       f0, f1, f2, f3, f4, Wc, Wcls, Wbox, wr2, wh2, fpad, sbuf);
    hipLaunchKernelGGL(conv_main, dim3(1600),  dim3(512), 0, stream, fpad, wr2, wh2, bC, sbuf);
    hipLaunchKernelGGL(finalize,  dim3(798),   dim3(256), 0, stream, sbuf, bcls, bbox, (float*)d_out);
}